// Round 2
// baseline (364.360 us; speedup 1.0000x reference)
//
#include <hip/hip_runtime.h>
#include <hip/hip_bf16.h>

#define N_NODES 50000
#define N_EDGES 800000
#define FEAT    128
#define N_TILES (N_NODES / 16)   // 3125, N_NODES % 16 == 0

using short8  = __attribute__((ext_vector_type(8))) short;
using float4v = __attribute__((ext_vector_type(4))) float;

// ---------------- workspace layout (int units) ----------------
// flag[16] | deg[50048] | fill[50048] | row_ptr[50048] | wsum f32[50048] | edges int2[800000]
// total ~7.2 MB

__device__ __forceinline__ short f2b(float f) {
    __hip_bfloat16 h = __float2bfloat16(f);           // RNE
    return (short)__builtin_bit_cast(unsigned short, h);
}

// Detect int64 vs int32 edge_index: int64 entries (<2^31) have zero high words.
__global__ void k_probe(const int* __restrict__ ei, int* __restrict__ flag) {
    int t = threadIdx.x;                               // 64 threads
    unsigned long long m = __ballot(ei[2 * t + 1] != 0);
    if (t == 0) flag[0] = (m == 0ULL) ? 1 : 0;
}

__global__ void k_zero(int* __restrict__ deg, int* __restrict__ fill) {
    int i = blockIdx.x * blockDim.x + threadIdx.x;
    if (i <= N_NODES) { deg[i] = 0; fill[i] = 0; }
}

__global__ void k_hist(const int* __restrict__ ei, const int* __restrict__ flag,
                       int* __restrict__ deg) {
    int e = blockIdx.x * blockDim.x + threadIdx.x;
    if (e >= N_EDGES) return;
    int sh  = flag[0];
    int dst = ei[(size_t)e << sh];
    if ((unsigned)dst >= N_NODES) dst = 0;
    atomicAdd(&deg[dst], 1);
}

// single-block exclusive scan over deg[0..N) -> row_ptr[0..N]
__global__ void k_scan(const int* __restrict__ deg, int* __restrict__ row_ptr) {
    __shared__ int part[1024];
    const int CH = (N_NODES + 1023) / 1024;            // 49
    int t = threadIdx.x;
    int begin = t * CH;
    int end   = begin + CH; if (end > N_NODES) end = N_NODES;
    int s = 0;
    for (int i = begin; i < end; ++i) s += deg[i];
    part[t] = s;
    __syncthreads();
    for (int off = 1; off < 1024; off <<= 1) {
        int v = (t >= off) ? part[t - off] : 0;
        __syncthreads();
        part[t] += v;
        __syncthreads();
    }
    int run = (t == 0) ? 0 : part[t - 1];
    for (int i = begin; i < end; ++i) { row_ptr[i] = run; run += deg[i]; }
    if (t == 1023) row_ptr[N_NODES] = part[1023];
}

__global__ void k_scatter(const int* __restrict__ ei, const float* __restrict__ wt,
                          const int* __restrict__ flag, const int* __restrict__ row_ptr,
                          int* __restrict__ fill, int2* __restrict__ edges) {
    int e = blockIdx.x * blockDim.x + threadIdx.x;
    if (e >= N_EDGES) return;
    int sh  = flag[0];
    int dst = ei[(size_t)e << sh];
    int src = ei[(size_t)(N_EDGES + e) << sh];
    if ((unsigned)dst >= N_NODES) dst = 0;
    if ((unsigned)src >= N_NODES) src = 0;
    int pos = row_ptr[dst] + atomicAdd(&fill[dst], 1);
    int2 rec; rec.x = src; rec.y = __float_as_int(wt[e]);
    edges[pos] = rec;
}

// agg[node][:] = sum_e w_e * x[src_e][:]  (fp32) -> d_out; wsum[node] = sum_e w_e
// one wave per node; lane l owns features 2l, 2l+1
__global__ __launch_bounds__(256) void k_agg(const int* __restrict__ row_ptr,
                                             const int2* __restrict__ edges,
                                             const float* __restrict__ x,
                                             float* __restrict__ out,
                                             float* __restrict__ wsum) {
    const int wave = threadIdx.x >> 6;
    const int lane = threadIdx.x & 63;
    const int node = blockIdx.x * 4 + wave;
    if (node >= N_NODES) return;

    const int start = row_ptr[node];
    const int end   = row_ptr[node + 1];

    float a0 = 0.f, a1 = 0.f, ws = 0.f;
    const float* xb = x + lane * 2;

    for (int e = start; e < end; ++e) {
        int2  rec = edges[e];
        unsigned s = (unsigned)rec.x; if (s >= N_NODES) s = 0;
        float w   = __int_as_float(rec.y);
        float2 h  = *(const float2*)(xb + (size_t)s * FEAT);
        a0 = fmaf(w, h.x, a0);
        a1 = fmaf(w, h.y, a1);
        ws += w;
    }

    *(float2*)(out + (size_t)node * FEAT + lane * 2) = make_float2(a0, a1);
    if (lane == 0) wsum[node] = ws;
}

// in-place: io (= d_out) holds agg fp32; compute io = agg @ W^T + wsum*b
// one wave = 16 rows; A/B cast fp32->bf16 in regs; fp32 accumulate (MFMA)
__global__ __launch_bounds__(256) void k_gemm(float* __restrict__ io,
                                              const float* __restrict__ W,
                                              const float* __restrict__ bias,
                                              const float* __restrict__ wsum) {
    const int wave = threadIdx.x >> 6;
    const int lane = threadIdx.x & 63;
    const int tile = blockIdx.x * 4 + wave;
    if (tile >= N_TILES) return;
    const int rowBase = tile * 16;
    const int m    = lane & 15;
    const int quad = lane >> 4;

    float4v acc[8];
    for (int i = 0; i < 8; ++i) acc[i] = (float4v){0.f, 0.f, 0.f, 0.f};

    for (int kk = 0; kk < 4; ++kk) {
        const int k0 = kk * 32 + quad * 8;
        // A[m][k]: m = lane&15, k = quad*8+j
        const float* ap = io + (size_t)(rowBase + m) * FEAT + k0;
        float4v a0 = *(const float4v*)(ap);
        float4v a1 = *(const float4v*)(ap + 4);
        short8 af;
        for (int j = 0; j < 4; ++j) { af[j] = f2b(a0[j]); af[4 + j] = f2b(a1[j]); }
        for (int nt = 0; nt < 8; ++nt) {
            // B[k][n] = W[n][k]: n = nt*16 + m
            const float* bp = W + (size_t)(nt * 16 + m) * FEAT + k0;
            float4v b0 = *(const float4v*)(bp);
            float4v b1 = *(const float4v*)(bp + 4);
            short8 bf;
            for (int j = 0; j < 4; ++j) { bf[j] = f2b(b0[j]); bf[4 + j] = f2b(b1[j]); }
            acc[nt] = __builtin_amdgcn_mfma_f32_16x16x32_bf16(af, bf, acc[nt], 0, 0, 0);
        }
    }

    // C/D layout: col = lane&15, row = quad*4 + r
    const int r0 = rowBase + quad * 4;
    float wsv[4];
    for (int r = 0; r < 4; ++r) wsv[r] = wsum[r0 + r];
    for (int nt = 0; nt < 8; ++nt) {
        const int col = nt * 16 + m;
        const float bc = bias[col];
        for (int r = 0; r < 4; ++r) {
            io[(size_t)(r0 + r) * FEAT + col] = acc[nt][r] + wsv[r] * bc;
        }
    }
}

extern "C" void kernel_launch(void* const* d_in, const int* in_sizes, int n_in,
                              void* d_out, int out_size, void* d_ws, size_t ws_size,
                              hipStream_t stream) {
    const float* x  = (const float*)d_in[0];
    const int*   ei = (const int*)d_in[1];
    const float* ew = (const float*)d_in[2];
    const float* W  = (const float*)d_in[3];
    const float* b  = (const float*)d_in[4];
    float* out = (float*)d_out;

    int*   flag    = (int*)d_ws;
    int*   deg     = flag + 16;
    int*   fill    = deg + 50048;
    int*   row_ptr = fill + 50048;
    float* wsum    = (float*)(row_ptr + 50048);
    int2*  edges   = (int2*)(wsum + 50048);            // byte off 800832, 8B-aligned

    k_probe  <<<1, 64, 0, stream>>>(ei, flag);
    k_zero   <<<(N_NODES + 256) / 256, 256, 0, stream>>>(deg, fill);
    k_hist   <<<N_EDGES / 256, 256, 0, stream>>>(ei, flag, deg);
    k_scan   <<<1, 1024, 0, stream>>>(deg, row_ptr);
    k_scatter<<<N_EDGES / 256, 256, 0, stream>>>(ei, ew, flag, row_ptr, fill, edges);
    k_agg    <<<(N_NODES + 3) / 4, 256, 0, stream>>>(row_ptr, edges, x, out, wsum);
    k_gemm   <<<(N_TILES + 3) / 4, 256, 0, stream>>>(out, W, b, wsum);
}

// Round 3
// 314.096 us; speedup vs baseline: 1.1600x; 1.1600x over previous
//
#include <hip/hip_runtime.h>
#include <hip/hip_bf16.h>

#define N_NODES 50000
#define N_EDGES 800000
#define FEAT    128
#define N_TILES (N_NODES / 16)   // 3125

using short8  = __attribute__((ext_vector_type(8))) short;
using float4v = __attribute__((ext_vector_type(4))) float;

// ---------------- workspace layout ----------------
// flag[16] | deg[50048] | fill[50048] | row_ptr[50048] | edges int2[800000] | hidden bf16[50000*128]
// = 64 + 600576 + 6400000 + 12800000 B ~= 19.8 MB

__device__ __forceinline__ short f2b(float f) {
    __hip_bfloat16 h = __float2bfloat16(f);           // RNE
    return (short)__builtin_bit_cast(unsigned short, h);
}

// zero counters + detect int64-vs-int32 edge_index (int64 low-words: high word == 0)
__global__ void k_init(const int* __restrict__ ei, int* __restrict__ flag,
                       int* __restrict__ deg, int* __restrict__ fill) {
    int i = blockIdx.x * blockDim.x + threadIdx.x;
    if (i <= N_NODES) { deg[i] = 0; fill[i] = 0; }
    if (blockIdx.x == 0 && threadIdx.x < 64) {
        unsigned long long m = __ballot(ei[2 * threadIdx.x + 1] != 0);
        if (threadIdx.x == 0) flag[0] = (m == 0ULL) ? 1 : 0;
    }
}

__global__ void k_hist(const int* __restrict__ ei, const int* __restrict__ flag,
                       int* __restrict__ deg) {
    int e = blockIdx.x * blockDim.x + threadIdx.x;
    if (e >= N_EDGES) return;
    int sh  = flag[0];
    int dst = ei[(size_t)e << sh];
    if ((unsigned)dst >= N_NODES) dst = 0;
    atomicAdd(&deg[dst], 1);
}

// single-block exclusive scan over deg[0..N) -> row_ptr[0..N]
__global__ void k_scan(const int* __restrict__ deg, int* __restrict__ row_ptr) {
    __shared__ int part[1024];
    const int CH = (N_NODES + 1023) / 1024;            // 49
    int t = threadIdx.x;
    int begin = t * CH;
    int end   = begin + CH; if (end > N_NODES) end = N_NODES;
    int s = 0;
    for (int i = begin; i < end; ++i) s += deg[i];
    part[t] = s;
    __syncthreads();
    for (int off = 1; off < 1024; off <<= 1) {
        int v = (t >= off) ? part[t - off] : 0;
        __syncthreads();
        part[t] += v;
        __syncthreads();
    }
    int run = (t == 0) ? 0 : part[t - 1];
    for (int i = begin; i < end; ++i) { row_ptr[i] = run; run += deg[i]; }
    if (t == 1023) row_ptr[N_NODES] = part[1023];
}

__global__ void k_scatter(const int* __restrict__ ei, const float* __restrict__ wt,
                          const int* __restrict__ flag, const int* __restrict__ row_ptr,
                          int* __restrict__ fill, int2* __restrict__ edges) {
    int e = blockIdx.x * blockDim.x + threadIdx.x;
    if (e >= N_EDGES) return;
    int sh  = flag[0];
    int dst = ei[(size_t)e << sh];
    int src = ei[(size_t)(N_EDGES + e) << sh];
    if ((unsigned)dst >= N_NODES) dst = 0;
    if ((unsigned)src >= N_NODES) src = 0;
    int pos = row_ptr[dst] + atomicAdd(&fill[dst], 1);
    int2 rec; rec.x = src; rec.y = __float_as_int(wt[e]);
    edges[pos] = rec;
}

// hidden[N,128] = bf16( x[N,128] @ W[128,128]^T + b )   (fp32 in, bf16 out)
// one wave = 16 rows; fp32->bf16 cast in regs; MFMA fp32 accumulate
__global__ __launch_bounds__(256) void k_gemm(const float* __restrict__ x,
                                              const float* __restrict__ W,
                                              const float* __restrict__ bias,
                                              unsigned short* __restrict__ hidden) {
    const int wave = threadIdx.x >> 6;
    const int lane = threadIdx.x & 63;
    const int tile = blockIdx.x * 4 + wave;
    if (tile >= N_TILES) return;
    const int rowBase = tile * 16;
    const int m    = lane & 15;
    const int quad = lane >> 4;

    float4v acc[8];
    for (int i = 0; i < 8; ++i) acc[i] = (float4v){0.f, 0.f, 0.f, 0.f};

    for (int kk = 0; kk < 4; ++kk) {
        const int k0 = kk * 32 + quad * 8;
        const float* ap = x + (size_t)(rowBase + m) * FEAT + k0;
        float4v a0 = *(const float4v*)(ap);
        float4v a1 = *(const float4v*)(ap + 4);
        short8 af;
        for (int j = 0; j < 4; ++j) { af[j] = f2b(a0[j]); af[4 + j] = f2b(a1[j]); }
        for (int nt = 0; nt < 8; ++nt) {
            const float* bp = W + (size_t)(nt * 16 + m) * FEAT + k0;
            float4v b0 = *(const float4v*)(bp);
            float4v b1 = *(const float4v*)(bp + 4);
            short8 bf;
            for (int j = 0; j < 4; ++j) { bf[j] = f2b(b0[j]); bf[4 + j] = f2b(b1[j]); }
            acc[nt] = __builtin_amdgcn_mfma_f32_16x16x32_bf16(af, bf, acc[nt], 0, 0, 0);
        }
    }

    // C/D layout: col = lane&15, row = quad*4 + r
    const int r0 = rowBase + quad * 4;
    for (int nt = 0; nt < 8; ++nt) {
        const int col = nt * 16 + m;
        const float bc = bias[col];
        for (int r = 0; r < 4; ++r) {
            hidden[(size_t)(r0 + r) * FEAT + col] =
                (unsigned short)__builtin_bit_cast(unsigned short, __float2bfloat16(acc[nt][r] + bc));
        }
    }
}

// out[node][:] = sum_e w_e * hidden[src_e][:]   (bf16 gather, fp32 accumulate)
// one wave per node; lane l owns features 2l, 2l+1 (one dword of the bf16 row)
__global__ __launch_bounds__(256) void k_agg(const int* __restrict__ row_ptr,
                                             const int2* __restrict__ edges,
                                             const unsigned int* __restrict__ hid,
                                             float* __restrict__ out) {
    const int wave = threadIdx.x >> 6;
    const int lane = threadIdx.x & 63;
    const int node = blockIdx.x * 4 + wave;
    if (node >= N_NODES) return;

    const int start = row_ptr[node];
    const int end   = row_ptr[node + 1];

    float a0 = 0.f, a1 = 0.f;

    int e = start;
    for (; e + 4 <= end; e += 4) {
        int2 r0 = edges[e];
        int2 r1 = edges[e + 1];
        int2 r2 = edges[e + 2];
        int2 r3 = edges[e + 3];
        unsigned h0 = hid[(size_t)r0.x * 64 + lane];
        unsigned h1 = hid[(size_t)r1.x * 64 + lane];
        unsigned h2 = hid[(size_t)r2.x * 64 + lane];
        unsigned h3 = hid[(size_t)r3.x * 64 + lane];
        float w0 = __int_as_float(r0.y), w1 = __int_as_float(r1.y);
        float w2 = __int_as_float(r2.y), w3 = __int_as_float(r3.y);
        a0 = fmaf(w0, __uint_as_float((h0 & 0xffffu) << 16), a0);
        a1 = fmaf(w0, __uint_as_float(h0 & 0xffff0000u), a1);
        a0 = fmaf(w1, __uint_as_float((h1 & 0xffffu) << 16), a0);
        a1 = fmaf(w1, __uint_as_float(h1 & 0xffff0000u), a1);
        a0 = fmaf(w2, __uint_as_float((h2 & 0xffffu) << 16), a0);
        a1 = fmaf(w2, __uint_as_float(h2 & 0xffff0000u), a1);
        a0 = fmaf(w3, __uint_as_float((h3 & 0xffffu) << 16), a0);
        a1 = fmaf(w3, __uint_as_float(h3 & 0xffff0000u), a1);
    }
    for (; e < end; ++e) {
        int2 rec = edges[e];
        float w  = __int_as_float(rec.y);
        unsigned h = hid[(size_t)rec.x * 64 + lane];
        a0 = fmaf(w, __uint_as_float((h & 0xffffu) << 16), a0);
        a1 = fmaf(w, __uint_as_float(h & 0xffff0000u), a1);
    }

    *(float2*)(out + (size_t)node * FEAT + lane * 2) = make_float2(a0, a1);
}

extern "C" void kernel_launch(void* const* d_in, const int* in_sizes, int n_in,
                              void* d_out, int out_size, void* d_ws, size_t ws_size,
                              hipStream_t stream) {
    const float* x  = (const float*)d_in[0];
    const int*   ei = (const int*)d_in[1];
    const float* ew = (const float*)d_in[2];
    const float* W  = (const float*)d_in[3];
    const float* b  = (const float*)d_in[4];
    float* out = (float*)d_out;

    int*  flag    = (int*)d_ws;
    int*  deg     = flag + 16;
    int*  fill    = deg + 50048;
    int*  row_ptr = fill + 50048;
    int2* edges   = (int2*)(row_ptr + 50048);                 // byte 600640, 8B-aligned
    unsigned short* hidden = (unsigned short*)(edges + N_EDGES); // byte 7000640, 16B-aligned

    k_init   <<<(N_NODES + 256) / 256, 256, 0, stream>>>(ei, flag, deg, fill);
    k_gemm   <<<(N_TILES + 3) / 4, 256, 0, stream>>>(x, W, b, hidden);
    k_hist   <<<N_EDGES / 256, 256, 0, stream>>>(ei, flag, deg);
    k_scan   <<<1, 1024, 0, stream>>>(deg, row_ptr);
    k_scatter<<<N_EDGES / 256, 256, 0, stream>>>(ei, ew, flag, row_ptr, fill, edges);
    k_agg    <<<(N_NODES + 3) / 4, 256, 0, stream>>>(row_ptr, edges, (const unsigned int*)hidden, out);
}

// Round 4
// 222.733 us; speedup vs baseline: 1.6359x; 1.4102x over previous
//
#include <hip/hip_runtime.h>
#include <hip/hip_bf16.h>

#define N_NODES 50000
#define N_EDGES 800000
#define FEAT    128
#define N_TILES (N_NODES / 16)          // 3125
#define NB_SCAN ((N_NODES + 255) / 256) // 196

using short8  = __attribute__((ext_vector_type(8))) short;
using float4v = __attribute__((ext_vector_type(4))) float;

// ---------------- workspace layout ----------------
// flag[16] | deg[50048] | fill[50048] | row_ptr[50048] | bsum[256] | edges int2[800000] | hidden bf16[50000*128]

__device__ __forceinline__ short f2b(float f) {
    __hip_bfloat16 h = __float2bfloat16(f);           // RNE
    return (short)__builtin_bit_cast(unsigned short, h);
}

// zero counters + detect int64-vs-int32 edge_index (int64 low-words: high word == 0)
__global__ void k_init(const int* __restrict__ ei, int* __restrict__ flag,
                       int* __restrict__ deg, int* __restrict__ fill) {
    int i = blockIdx.x * blockDim.x + threadIdx.x;
    if (i <= N_NODES) { deg[i] = 0; fill[i] = 0; }
    if (blockIdx.x == 0 && threadIdx.x < 64) {
        unsigned long long m = __ballot(ei[2 * threadIdx.x + 1] != 0);
        if (threadIdx.x == 0) flag[0] = (m == 0ULL) ? 1 : 0;
    }
}

__global__ void k_hist(const int* __restrict__ ei, const int* __restrict__ flag,
                       int* __restrict__ deg) {
    int e = blockIdx.x * blockDim.x + threadIdx.x;
    if (e >= N_EDGES) return;
    int sh  = flag[0];
    int dst = ei[(size_t)e << sh];
    if ((unsigned)dst >= N_NODES) dst = 0;
    atomicAdd(&deg[dst], 1);
}

// ---- parallel scan, phase 1: per-block (256-elem) sums ----
__global__ __launch_bounds__(256) void k_bsum(const int* __restrict__ deg, int* __restrict__ bsum) {
    int t = threadIdx.x;
    int i = blockIdx.x * 256 + t;
    int v = (i < N_NODES) ? deg[i] : 0;
    for (int off = 32; off > 0; off >>= 1) v += __shfl_down(v, off, 64);
    __shared__ int ws[4];
    if ((t & 63) == 0) ws[t >> 6] = v;
    __syncthreads();
    if (t == 0) bsum[blockIdx.x] = ws[0] + ws[1] + ws[2] + ws[3];
}

// ---- phase 2: scan the 196 block sums (one block); also writes row_ptr[N] ----
__global__ __launch_bounds__(256) void k_bscan(int* __restrict__ bsum, int* __restrict__ row_ptr) {
    int t = threadIdx.x;
    int v = (t < NB_SCAN) ? bsum[t] : 0;
    __shared__ int sh[256];
    sh[t] = v;
    __syncthreads();
    for (int off = 1; off < 256; off <<= 1) {
        int u = (t >= off) ? sh[t - off] : 0;
        __syncthreads();
        sh[t] += u;
        __syncthreads();
    }
    if (t < NB_SCAN) bsum[t] = sh[t] - v;          // exclusive block offset
    if (t == 255) row_ptr[N_NODES] = sh[255];      // total = E
}

// ---- phase 3: in-block scan + block offset -> row_ptr ----
__global__ __launch_bounds__(256) void k_wpos(const int* __restrict__ deg, const int* __restrict__ bsum,
                                              int* __restrict__ row_ptr) {
    int t = threadIdx.x;
    int i = blockIdx.x * 256 + t;
    int v = (i < N_NODES) ? deg[i] : 0;
    __shared__ int sh[256];
    sh[t] = v;
    __syncthreads();
    for (int off = 1; off < 256; off <<= 1) {
        int u = (t >= off) ? sh[t - off] : 0;
        __syncthreads();
        sh[t] += u;
        __syncthreads();
    }
    if (i < N_NODES) row_ptr[i] = bsum[blockIdx.x] + sh[t] - v;
}

__global__ void k_scatter(const int* __restrict__ ei, const float* __restrict__ wt,
                          const int* __restrict__ flag, const int* __restrict__ row_ptr,
                          int* __restrict__ fill, int2* __restrict__ edges) {
    int e = blockIdx.x * blockDim.x + threadIdx.x;
    if (e >= N_EDGES) return;
    int sh  = flag[0];
    int dst = ei[(size_t)e << sh];
    int src = ei[(size_t)(N_EDGES + e) << sh];
    if ((unsigned)dst >= N_NODES) dst = 0;
    if ((unsigned)src >= N_NODES) src = 0;
    int pos = row_ptr[dst] + atomicAdd(&fill[dst], 1);
    int2 rec; rec.x = src; rec.y = __float_as_int(wt[e]);
    edges[pos] = rec;
}

// hidden[N,128] = bf16( x[N,128] @ W[128,128]^T + b )
// W staged once per block into LDS as bf16 (row pad 8 shorts -> bank-balanced b128 reads)
__global__ __launch_bounds__(256) void k_gemm(const float* __restrict__ x,
                                              const float* __restrict__ W,
                                              const float* __restrict__ bias,
                                              unsigned short* __restrict__ hidden) {
    __shared__ __align__(16) unsigned short Wlds[128 * 136];

    const int t = threadIdx.x;
    // cooperative W f32->bf16 staging: iteration j loads lane-consecutive float4s
    for (int j = 0; j < 16; ++j) {
        int idx4 = j * 256 + t;                     // float4 index, 0..4095
        float4v wv = *(const float4v*)(W + (size_t)idx4 * 4);
        int r = (idx4 * 4) >> 7;
        int c = (idx4 * 4) & 127;
        unsigned short* p = &Wlds[r * 136 + c];
        p[0] = (unsigned short)f2b(wv[0]);
        p[1] = (unsigned short)f2b(wv[1]);
        p[2] = (unsigned short)f2b(wv[2]);
        p[3] = (unsigned short)f2b(wv[3]);
    }
    __syncthreads();

    const int wave = t >> 6;
    const int lane = t & 63;
    int tile = blockIdx.x * 4 + wave;
    if (tile >= N_TILES) tile = N_TILES - 1;        // clamp: redundant identical work, no divergent exit
    const int rowBase = tile * 16;
    const int m    = lane & 15;
    const int quad = lane >> 4;

    float4v acc[8];
    for (int i = 0; i < 8; ++i) acc[i] = (float4v){0.f, 0.f, 0.f, 0.f};

    for (int kk = 0; kk < 4; ++kk) {
        const int k0 = kk * 32 + quad * 8;
        const float* ap = x + (size_t)(rowBase + m) * FEAT + k0;
        float4v a0 = *(const float4v*)(ap);
        float4v a1 = *(const float4v*)(ap + 4);
        short8 af;
        for (int j = 0; j < 4; ++j) { af[j] = f2b(a0[j]); af[4 + j] = f2b(a1[j]); }
        for (int nt = 0; nt < 8; ++nt) {
            short8 bf = *(const short8*)&Wlds[(nt * 16 + m) * 136 + k0];
            acc[nt] = __builtin_amdgcn_mfma_f32_16x16x32_bf16(af, bf, acc[nt], 0, 0, 0);
        }
    }

    // C/D layout: col = lane&15, row = quad*4 + r
    const int r0 = rowBase + quad * 4;
    for (int nt = 0; nt < 8; ++nt) {
        const int col = nt * 16 + m;
        const float bc = bias[col];
        for (int r = 0; r < 4; ++r) {
            hidden[(size_t)(r0 + r) * FEAT + col] =
                (unsigned short)__builtin_bit_cast(unsigned short, __float2bfloat16(acc[nt][r] + bc));
        }
    }
}

// out[node][:] = sum_e w_e * hidden[src_e][:]   (bf16 gather, fp32 accumulate)
__global__ __launch_bounds__(256) void k_agg(const int* __restrict__ row_ptr,
                                             const int2* __restrict__ edges,
                                             const unsigned int* __restrict__ hid,
                                             float* __restrict__ out) {
    const int wave = threadIdx.x >> 6;
    const int lane = threadIdx.x & 63;
    const int node = blockIdx.x * 4 + wave;
    if (node >= N_NODES) return;

    const int start = row_ptr[node];
    const int end   = row_ptr[node + 1];

    float a0 = 0.f, a1 = 0.f;

    int e = start;
    for (; e + 4 <= end; e += 4) {
        int2 r0 = edges[e];
        int2 r1 = edges[e + 1];
        int2 r2 = edges[e + 2];
        int2 r3 = edges[e + 3];
        unsigned h0 = hid[(size_t)r0.x * 64 + lane];
        unsigned h1 = hid[(size_t)r1.x * 64 + lane];
        unsigned h2 = hid[(size_t)r2.x * 64 + lane];
        unsigned h3 = hid[(size_t)r3.x * 64 + lane];
        float w0 = __int_as_float(r0.y), w1 = __int_as_float(r1.y);
        float w2 = __int_as_float(r2.y), w3 = __int_as_float(r3.y);
        a0 = fmaf(w0, __uint_as_float((h0 & 0xffffu) << 16), a0);
        a1 = fmaf(w0, __uint_as_float(h0 & 0xffff0000u), a1);
        a0 = fmaf(w1, __uint_as_float((h1 & 0xffffu) << 16), a0);
        a1 = fmaf(w1, __uint_as_float(h1 & 0xffff0000u), a1);
        a0 = fmaf(w2, __uint_as_float((h2 & 0xffffu) << 16), a0);
        a1 = fmaf(w2, __uint_as_float(h2 & 0xffff0000u), a1);
        a0 = fmaf(w3, __uint_as_float((h3 & 0xffffu) << 16), a0);
        a1 = fmaf(w3, __uint_as_float(h3 & 0xffff0000u), a1);
    }
    for (; e < end; ++e) {
        int2 rec = edges[e];
        float w  = __int_as_float(rec.y);
        unsigned h = hid[(size_t)rec.x * 64 + lane];
        a0 = fmaf(w, __uint_as_float((h & 0xffffu) << 16), a0);
        a1 = fmaf(w, __uint_as_float(h & 0xffff0000u), a1);
    }

    *(float2*)(out + (size_t)node * FEAT + lane * 2) = make_float2(a0, a1);
}

extern "C" void kernel_launch(void* const* d_in, const int* in_sizes, int n_in,
                              void* d_out, int out_size, void* d_ws, size_t ws_size,
                              hipStream_t stream) {
    const float* x  = (const float*)d_in[0];
    const int*   ei = (const int*)d_in[1];
    const float* ew = (const float*)d_in[2];
    const float* W  = (const float*)d_in[3];
    const float* b  = (const float*)d_in[4];
    float* out = (float*)d_out;

    int*  flag    = (int*)d_ws;
    int*  deg     = flag + 16;
    int*  fill    = deg + 50048;
    int*  row_ptr = fill + 50048;
    int*  bsum    = row_ptr + 50048;
    int2* edges   = (int2*)(bsum + 256);                      // 8B-aligned
    unsigned short* hidden = (unsigned short*)(edges + N_EDGES);

    k_init   <<<(N_NODES + 256) / 256, 256, 0, stream>>>(ei, flag, deg, fill);
    k_gemm   <<<(N_TILES + 3) / 4, 256, 0, stream>>>(x, W, b, hidden);
    k_hist   <<<N_EDGES / 256, 256, 0, stream>>>(ei, flag, deg);
    k_bsum   <<<NB_SCAN, 256, 0, stream>>>(deg, bsum);
    k_bscan  <<<1, 256, 0, stream>>>(bsum, row_ptr);
    k_wpos   <<<NB_SCAN, 256, 0, stream>>>(deg, bsum, row_ptr);
    k_scatter<<<N_EDGES / 256, 256, 0, stream>>>(ei, ew, flag, row_ptr, fill, edges);
    k_agg    <<<(N_NODES + 3) / 4, 256, 0, stream>>>(row_ptr, edges, (const unsigned int*)hidden, out);
}

// Round 5
// 189.096 us; speedup vs baseline: 1.9269x; 1.1779x over previous
//
#include <hip/hip_runtime.h>
#include <hip/hip_bf16.h>

#define N_NODES 50000
#define N_EDGES 800000
#define FEAT    128
#define N_TILES (N_NODES / 16)          // 3125
#define MAXD    32                      // slots per node; Poisson(16) P(deg>=32)~2.6e-4
#define OVF_CAP 16384

using short8  = __attribute__((ext_vector_type(8))) short;
using float4v = __attribute__((ext_vector_type(4))) float;

// ---------------- workspace layout (ints) ----------------
// flag[16] (flag0=int64flag, flag1=ovf cursor) | fill[50048] | ovf int2[16384]
// | slots uint[50000*32] | hidden ushort[50000*128]   total ~19.5 MB

__device__ __forceinline__ unsigned short f2b(float f) {
    __hip_bfloat16 h = __float2bfloat16(f);           // RNE
    return __builtin_bit_cast(unsigned short, h);
}

// zero fill + ovf cursor; detect int64-vs-int32 edge_index (int64: odd words are 0)
__global__ void k_init(const int* __restrict__ ei, int* __restrict__ flag,
                       int* __restrict__ fill) {
    int i = blockIdx.x * blockDim.x + threadIdx.x;
    if (i < N_NODES) fill[i] = 0;
    if (blockIdx.x == 0 && threadIdx.x < 64) {
        unsigned long long m = __ballot(ei[2 * threadIdx.x + 1] != 0);
        if (threadIdx.x == 0) { flag[0] = (m == 0ULL) ? 1 : 0; flag[1] = 0; }
    }
}

// hidden[N,128] = bf16( x[N,128] @ W[128,128]^T + b )
// W staged once per block into LDS as bf16 (row pad 8 shorts -> bank-balanced b128 reads)
__global__ __launch_bounds__(256) void k_gemm(const float* __restrict__ x,
                                              const float* __restrict__ W,
                                              const float* __restrict__ bias,
                                              unsigned short* __restrict__ hidden) {
    __shared__ __align__(16) unsigned short Wlds[128 * 136];

    const int t = threadIdx.x;
    for (int j = 0; j < 16; ++j) {
        int idx4 = j * 256 + t;                     // float4 index, 0..4095
        float4v wv = *(const float4v*)(W + (size_t)idx4 * 4);
        int r = (idx4 * 4) >> 7;
        int c = (idx4 * 4) & 127;
        unsigned short* p = &Wlds[r * 136 + c];
        p[0] = f2b(wv[0]); p[1] = f2b(wv[1]); p[2] = f2b(wv[2]); p[3] = f2b(wv[3]);
    }
    __syncthreads();

    const int wave = t >> 6;
    const int lane = t & 63;
    int tile = blockIdx.x * 4 + wave;
    if (tile >= N_TILES) tile = N_TILES - 1;        // clamp: redundant work, no divergent exit
    const int rowBase = tile * 16;
    const int m    = lane & 15;
    const int quad = lane >> 4;

    float4v acc[8];
    for (int i = 0; i < 8; ++i) acc[i] = (float4v){0.f, 0.f, 0.f, 0.f};

    for (int kk = 0; kk < 4; ++kk) {
        const int k0 = kk * 32 + quad * 8;
        const float* ap = x + (size_t)(rowBase + m) * FEAT + k0;
        float4v a0 = *(const float4v*)(ap);
        float4v a1 = *(const float4v*)(ap + 4);
        short8 af;
        for (int j = 0; j < 4; ++j) { af[j] = (short)f2b(a0[j]); af[4 + j] = (short)f2b(a1[j]); }
        for (int nt = 0; nt < 8; ++nt) {
            short8 bf = *(const short8*)&Wlds[(nt * 16 + m) * 136 + k0];
            acc[nt] = __builtin_amdgcn_mfma_f32_16x16x32_bf16(af, bf, acc[nt], 0, 0, 0);
        }
    }

    // C/D layout: col = lane&15, row = quad*4 + r
    const int r0 = rowBase + quad * 4;
    for (int nt = 0; nt < 8; ++nt) {
        const int col = nt * 16 + m;
        const float bc = bias[col];
        for (int r = 0; r < 4; ++r) {
            hidden[(size_t)(r0 + r) * FEAT + col] = f2b(acc[nt][r] + bc);
        }
    }
}

// single-pass scatter into fixed slots; record packed to 4B: [w_bf16:16 | src:16]
__global__ void k_scatter(const int* __restrict__ ei, const float* __restrict__ wt,
                          const int* __restrict__ flag, int* __restrict__ fill,
                          unsigned int* __restrict__ slots, int2* __restrict__ ovf) {
    int e = blockIdx.x * blockDim.x + threadIdx.x;
    if (e >= N_EDGES) return;
    int sh  = flag[0];
    int dst = ei[(size_t)e << sh];
    int src = ei[(size_t)(N_EDGES + e) << sh];
    if ((unsigned)dst >= N_NODES) dst = 0;
    if ((unsigned)src >= N_NODES) src = 0;
    unsigned int rec = ((unsigned int)f2b(wt[e]) << 16) | (unsigned int)src;
    int pos = atomicAdd(&fill[dst], 1);
    if (pos < MAXD) {
        slots[(size_t)dst * MAXD + pos] = rec;
    } else {
        int op = atomicAdd((int*)&((int*)flag)[1], 1);
        if (op < OVF_CAP) { int2 r; r.x = dst; r.y = (int)rec; ovf[op] = r; }
    }
}

// out[node][:] = sum_slots w_e * hidden[src_e][:]   (bf16 gather, fp32 accumulate)
__global__ __launch_bounds__(256) void k_agg(const int* __restrict__ fill,
                                             const unsigned int* __restrict__ slots,
                                             const unsigned int* __restrict__ hid,
                                             float* __restrict__ out) {
    const int wave = threadIdx.x >> 6;
    const int lane = threadIdx.x & 63;
    const int node = blockIdx.x * 4 + wave;
    if (node >= N_NODES) return;

    int deg = fill[node];
    if (deg > MAXD) deg = MAXD;
    const unsigned int* sl = slots + (size_t)node * MAXD;

    float a0 = 0.f, a1 = 0.f;

    int e = 0;
    for (; e + 4 <= deg; e += 4) {
        unsigned r0 = sl[e];
        unsigned r1 = sl[e + 1];
        unsigned r2 = sl[e + 2];
        unsigned r3 = sl[e + 3];
        unsigned h0 = hid[(size_t)(r0 & 0xffffu) * 64 + lane];
        unsigned h1 = hid[(size_t)(r1 & 0xffffu) * 64 + lane];
        unsigned h2 = hid[(size_t)(r2 & 0xffffu) * 64 + lane];
        unsigned h3 = hid[(size_t)(r3 & 0xffffu) * 64 + lane];
        float w0 = __uint_as_float(r0 & 0xffff0000u);
        float w1 = __uint_as_float(r1 & 0xffff0000u);
        float w2 = __uint_as_float(r2 & 0xffff0000u);
        float w3 = __uint_as_float(r3 & 0xffff0000u);
        a0 = fmaf(w0, __uint_as_float((h0 & 0xffffu) << 16), a0);
        a1 = fmaf(w0, __uint_as_float(h0 & 0xffff0000u), a1);
        a0 = fmaf(w1, __uint_as_float((h1 & 0xffffu) << 16), a0);
        a1 = fmaf(w1, __uint_as_float(h1 & 0xffff0000u), a1);
        a0 = fmaf(w2, __uint_as_float((h2 & 0xffffu) << 16), a0);
        a1 = fmaf(w2, __uint_as_float(h2 & 0xffff0000u), a1);
        a0 = fmaf(w3, __uint_as_float((h3 & 0xffffu) << 16), a0);
        a1 = fmaf(w3, __uint_as_float(h3 & 0xffff0000u), a1);
    }
    for (; e < deg; ++e) {
        unsigned r = sl[e];
        unsigned h = hid[(size_t)(r & 0xffffu) * 64 + lane];
        float w = __uint_as_float(r & 0xffff0000u);
        a0 = fmaf(w, __uint_as_float((h & 0xffffu) << 16), a0);
        a1 = fmaf(w, __uint_as_float(h & 0xffff0000u), a1);
    }

    *(float2*)(out + (size_t)node * FEAT + lane * 2) = make_float2(a0, a1);
}

// rare overflow edges: fp32 atomic add onto out (expected ~0-20 edges)
__global__ __launch_bounds__(256) void k_ovf(const int* __restrict__ flag,
                                             const int2* __restrict__ ovf,
                                             const unsigned int* __restrict__ hid,
                                             float* __restrict__ out) {
    const int wave = threadIdx.x >> 6;
    const int lane = threadIdx.x & 63;
    int n = flag[1];
    if (n > OVF_CAP) n = OVF_CAP;
    for (int i = wave; i < n; i += 4) {
        int2 r = ovf[i];
        unsigned rec = (unsigned)r.y;
        float w = __uint_as_float(rec & 0xffff0000u);
        unsigned h = hid[(size_t)(rec & 0xffffu) * 64 + lane];
        float* o = out + (size_t)r.x * FEAT + lane * 2;
        atomicAdd(o,     w * __uint_as_float((h & 0xffffu) << 16));
        atomicAdd(o + 1, w * __uint_as_float(h & 0xffff0000u));
    }
}

extern "C" void kernel_launch(void* const* d_in, const int* in_sizes, int n_in,
                              void* d_out, int out_size, void* d_ws, size_t ws_size,
                              hipStream_t stream) {
    const float* x  = (const float*)d_in[0];
    const int*   ei = (const int*)d_in[1];
    const float* ew = (const float*)d_in[2];
    const float* W  = (const float*)d_in[3];
    const float* b  = (const float*)d_in[4];
    float* out = (float*)d_out;

    int*  flag = (int*)d_ws;
    int*  fill = flag + 16;
    int2* ovf  = (int2*)(fill + 50048);
    unsigned int* slots = (unsigned int*)(ovf + OVF_CAP);
    unsigned short* hidden = (unsigned short*)(slots + (size_t)N_NODES * MAXD);

    k_init   <<<(N_NODES + 255) / 256, 256, 0, stream>>>(ei, flag, fill);
    k_gemm   <<<(N_TILES + 3) / 4, 256, 0, stream>>>(x, W, b, hidden);
    k_scatter<<<N_EDGES / 256, 256, 0, stream>>>(ei, ew, flag, fill, slots, ovf);
    k_agg    <<<(N_NODES + 3) / 4, 256, 0, stream>>>(fill, slots, (const unsigned int*)hidden, out);
    k_ovf    <<<1, 256, 0, stream>>>(flag, ovf, (const unsigned int*)hidden, out);
}

// Round 6
// 176.355 us; speedup vs baseline: 2.0661x; 1.0722x over previous
//
#include <hip/hip_runtime.h>
#include <hip/hip_bf16.h>

#define N_NODES 50000
#define N_EDGES 800000
#define FEAT    128
#define N_TILES (N_NODES / 16)          // 3125
#define MAXD    32                      // slots per node; Poisson(16) P(deg>=32)~2.6e-4
#define OVF_CAP 16384
#define NODES_PER_GRP 6250              // 50000 / 8
#define CHUNK   2048
#define NCHUNK  ((N_EDGES + CHUNK - 1) / CHUNK)   // 391

using short8  = __attribute__((ext_vector_type(8))) short;
using float4v = __attribute__((ext_vector_type(4))) float;

// ---------------- workspace layout (ints) ----------------
// flag[16] (flag0=int64flag, flag1=ovf cursor) | fill[50048] | ovf int2[16384]
// | slots uint[50000*32] | hidden ushort[50000*128]   total ~19.5 MB

__device__ __forceinline__ unsigned short f2b(float f) {
    __hip_bfloat16 h = __float2bfloat16(f);           // RNE
    return __builtin_bit_cast(unsigned short, h);
}

// zero fill + ovf cursor; detect int64-vs-int32 edge_index (int64: odd words are 0)
__global__ void k_init(const int* __restrict__ ei, int* __restrict__ flag,
                       int* __restrict__ fill) {
    int i = blockIdx.x * blockDim.x + threadIdx.x;
    if (i < N_NODES) fill[i] = 0;
    if (blockIdx.x == 0 && threadIdx.x < 64) {
        unsigned long long m = __ballot(ei[2 * threadIdx.x + 1] != 0);
        if (threadIdx.x == 0) { flag[0] = (m == 0ULL) ? 1 : 0; flag[1] = 0; }
    }
}

// hidden[N,128] = bf16( x[N,128] @ W[128,128]^T + b )
// W staged once per block into LDS as bf16 (row pad 8 shorts -> bank-balanced b128 reads)
__global__ __launch_bounds__(256) void k_gemm(const float* __restrict__ x,
                                              const float* __restrict__ W,
                                              const float* __restrict__ bias,
                                              unsigned short* __restrict__ hidden) {
    __shared__ __align__(16) unsigned short Wlds[128 * 136];

    const int t = threadIdx.x;
    for (int j = 0; j < 16; ++j) {
        int idx4 = j * 256 + t;                     // float4 index, 0..4095
        float4v wv = *(const float4v*)(W + (size_t)idx4 * 4);
        int r = (idx4 * 4) >> 7;
        int c = (idx4 * 4) & 127;
        unsigned short* p = &Wlds[r * 136 + c];
        p[0] = f2b(wv[0]); p[1] = f2b(wv[1]); p[2] = f2b(wv[2]); p[3] = f2b(wv[3]);
    }
    __syncthreads();

    const int wave = t >> 6;
    const int lane = t & 63;
    int tile = blockIdx.x * 4 + wave;
    if (tile >= N_TILES) tile = N_TILES - 1;        // clamp: redundant work, no divergent exit
    const int rowBase = tile * 16;
    const int m    = lane & 15;
    const int quad = lane >> 4;

    float4v acc[8];
    for (int i = 0; i < 8; ++i) acc[i] = (float4v){0.f, 0.f, 0.f, 0.f};

    for (int kk = 0; kk < 4; ++kk) {
        const int k0 = kk * 32 + quad * 8;
        const float* ap = x + (size_t)(rowBase + m) * FEAT + k0;
        float4v a0 = *(const float4v*)(ap);
        float4v a1 = *(const float4v*)(ap + 4);
        short8 af;
        for (int j = 0; j < 4; ++j) { af[j] = (short)f2b(a0[j]); af[4 + j] = (short)f2b(a1[j]); }
        for (int nt = 0; nt < 8; ++nt) {
            short8 bf = *(const short8*)&Wlds[(nt * 16 + m) * 136 + k0];
            acc[nt] = __builtin_amdgcn_mfma_f32_16x16x32_bf16(af, bf, acc[nt], 0, 0, 0);
        }
    }

    // C/D layout: col = lane&15, row = quad*4 + r
    const int r0 = rowBase + quad * 4;
    for (int nt = 0; nt < 8; ++nt) {
        const int col = nt * 16 + m;
        const float bc = bias[col];
        for (int r = 0; r < 4; ++r) {
            hidden[(size_t)(r0 + r) * FEAT + col] = f2b(acc[nt][r] + bc);
        }
    }
}

// XCD-grouped single-pass scatter: group g = blockIdx&7 (presumed XCD) handles
// dst in [g*6250,(g+1)*6250) so all stores to a slots line come from one XCD
// and merge in its L2 (kills the 48MB partial-line writeback). Correct for ANY
// block->XCD mapping; the mapping only affects merging efficiency.
__global__ __launch_bounds__(256) void k_scatter(const int* __restrict__ ei,
                                                 const float* __restrict__ wt,
                                                 const int* __restrict__ flag,
                                                 int* __restrict__ fill,
                                                 unsigned int* __restrict__ slots,
                                                 int2* __restrict__ ovf) {
    const int grp = blockIdx.x & 7;
    const int lo  = grp * NODES_PER_GRP;
    const int hi  = lo + NODES_PER_GRP;
    const int sh  = flag[0];
    const int e0  = (blockIdx.x >> 3) * CHUNK + threadIdx.x;

    for (int i = 0; i < CHUNK / 256; ++i) {
        int e = e0 + i * 256;
        if (e >= N_EDGES) break;
        int dst = ei[(size_t)e << sh];
        if ((unsigned)dst >= N_NODES) dst = 0;
        if (dst < lo || dst >= hi) continue;
        int src = ei[(size_t)(N_EDGES + e) << sh];
        if ((unsigned)src >= N_NODES) src = 0;
        unsigned int rec = ((unsigned int)f2b(wt[e]) << 16) | (unsigned int)src;
        int pos = atomicAdd(&fill[dst], 1);
        if (pos < MAXD) {
            slots[(size_t)dst * MAXD + pos] = rec;
        } else {
            int op = atomicAdd((int*)&((int*)flag)[1], 1);
            if (op < OVF_CAP) { int2 r; r.x = dst; r.y = (int)rec; ovf[op] = r; }
        }
    }
}

// out[node][:] = sum_slots w_e * hidden[src_e][:]   (bf16 gather, fp32 accumulate)
__global__ __launch_bounds__(256) void k_agg(const int* __restrict__ fill,
                                             const unsigned int* __restrict__ slots,
                                             const unsigned int* __restrict__ hid,
                                             float* __restrict__ out) {
    const int wave = threadIdx.x >> 6;
    const int lane = threadIdx.x & 63;
    const int node = blockIdx.x * 4 + wave;
    if (node >= N_NODES) return;

    int deg = fill[node];
    if (deg > MAXD) deg = MAXD;
    const unsigned int* sl = slots + (size_t)node * MAXD;

    float a0 = 0.f, a1 = 0.f;

    int e = 0;
    for (; e + 4 <= deg; e += 4) {
        unsigned r0 = sl[e];
        unsigned r1 = sl[e + 1];
        unsigned r2 = sl[e + 2];
        unsigned r3 = sl[e + 3];
        unsigned h0 = hid[(size_t)(r0 & 0xffffu) * 64 + lane];
        unsigned h1 = hid[(size_t)(r1 & 0xffffu) * 64 + lane];
        unsigned h2 = hid[(size_t)(r2 & 0xffffu) * 64 + lane];
        unsigned h3 = hid[(size_t)(r3 & 0xffffu) * 64 + lane];
        float w0 = __uint_as_float(r0 & 0xffff0000u);
        float w1 = __uint_as_float(r1 & 0xffff0000u);
        float w2 = __uint_as_float(r2 & 0xffff0000u);
        float w3 = __uint_as_float(r3 & 0xffff0000u);
        a0 = fmaf(w0, __uint_as_float((h0 & 0xffffu) << 16), a0);
        a1 = fmaf(w0, __uint_as_float(h0 & 0xffff0000u), a1);
        a0 = fmaf(w1, __uint_as_float((h1 & 0xffffu) << 16), a0);
        a1 = fmaf(w1, __uint_as_float(h1 & 0xffff0000u), a1);
        a0 = fmaf(w2, __uint_as_float((h2 & 0xffffu) << 16), a0);
        a1 = fmaf(w2, __uint_as_float(h2 & 0xffff0000u), a1);
        a0 = fmaf(w3, __uint_as_float((h3 & 0xffffu) << 16), a0);
        a1 = fmaf(w3, __uint_as_float(h3 & 0xffff0000u), a1);
    }
    for (; e < deg; ++e) {
        unsigned r = sl[e];
        unsigned h = hid[(size_t)(r & 0xffffu) * 64 + lane];
        float w = __uint_as_float(r & 0xffff0000u);
        a0 = fmaf(w, __uint_as_float((h & 0xffffu) << 16), a0);
        a1 = fmaf(w, __uint_as_float(h & 0xffff0000u), a1);
    }

    *(float2*)(out + (size_t)node * FEAT + lane * 2) = make_float2(a0, a1);
}

// rare overflow edges: fp32 atomic add onto out (expected ~0-20 edges)
__global__ __launch_bounds__(256) void k_ovf(const int* __restrict__ flag,
                                             const int2* __restrict__ ovf,
                                             const unsigned int* __restrict__ hid,
                                             float* __restrict__ out) {
    const int wave = threadIdx.x >> 6;
    const int lane = threadIdx.x & 63;
    int n = flag[1];
    if (n > OVF_CAP) n = OVF_CAP;
    for (int i = wave; i < n; i += 4) {
        int2 r = ovf[i];
        unsigned rec = (unsigned)r.y;
        float w = __uint_as_float(rec & 0xffff0000u);
        unsigned h = hid[(size_t)(rec & 0xffffu) * 64 + lane];
        float* o = out + (size_t)r.x * FEAT + lane * 2;
        atomicAdd(o,     w * __uint_as_float((h & 0xffffu) << 16));
        atomicAdd(o + 1, w * __uint_as_float(h & 0xffff0000u));
    }
}

extern "C" void kernel_launch(void* const* d_in, const int* in_sizes, int n_in,
                              void* d_out, int out_size, void* d_ws, size_t ws_size,
                              hipStream_t stream) {
    const float* x  = (const float*)d_in[0];
    const int*   ei = (const int*)d_in[1];
    const float* ew = (const float*)d_in[2];
    const float* W  = (const float*)d_in[3];
    const float* b  = (const float*)d_in[4];
    float* out = (float*)d_out;

    int*  flag = (int*)d_ws;
    int*  fill = flag + 16;
    int2* ovf  = (int2*)(fill + 50048);
    unsigned int* slots = (unsigned int*)(ovf + OVF_CAP);
    unsigned short* hidden = (unsigned short*)(slots + (size_t)N_NODES * MAXD);

    k_init   <<<(N_NODES + 255) / 256, 256, 0, stream>>>(ei, flag, fill);
    k_gemm   <<<(N_TILES + 3) / 4, 256, 0, stream>>>(x, W, b, hidden);
    k_scatter<<<NCHUNK * 8, 256, 0, stream>>>(ei, ew, flag, fill, slots, ovf);
    k_agg    <<<(N_NODES + 3) / 4, 256, 0, stream>>>(fill, slots, (const unsigned int*)hidden, out);
    k_ovf    <<<1, 256, 0, stream>>>(flag, ovf, (const unsigned int*)hidden, out);
}

// Round 7
// 173.315 us; speedup vs baseline: 2.1023x; 1.0175x over previous
//
#include <hip/hip_runtime.h>
#include <hip/hip_bf16.h>

#define N_NODES 50000
#define N_EDGES 800000
#define FEAT    128
#define N_TILES (N_NODES / 16)          // 3125
#define GEMM_BLOCKS 784                  // 782 needed (3125/4), padded to mult of 8
#define MAXD    32                       // slots per node; Poisson(16) P(deg>=32)~2.6e-4
#define OVF_CAP 16384
#define NODES_PER_GRP 6250               // 50000 / 8
#define CHUNK   2048
#define NCHUNK  ((N_EDGES + CHUNK - 1) / CHUNK)   // 391

using short8  = __attribute__((ext_vector_type(8))) short;
using float4v = __attribute__((ext_vector_type(4))) float;

// ---------------- workspace layout (bytes) ----------------
// flag[16 ints] @0 | fill[50048] @64 | ovf int2[16384] @200256 | slots uint[50000*32] @331328
// | hidden ushort[50000*128] @6731328   total ~19.5 MB

__device__ __forceinline__ unsigned short f2b(float f) {
    __hip_bfloat16 h = __float2bfloat16(f);           // RNE
    return __builtin_bit_cast(unsigned short, h);
}

// zero fill + ovf cursor; detect int64-vs-int32 edge_index (int64: odd words are 0)
__global__ void k_init(const int* __restrict__ ei, int* __restrict__ flag,
                       int* __restrict__ fill) {
    int i = blockIdx.x * blockDim.x + threadIdx.x;
    if (i < N_NODES) fill[i] = 0;
    if (blockIdx.x == 0 && threadIdx.x < 64) {
        unsigned long long m = __ballot(ei[2 * threadIdx.x + 1] != 0);
        if (threadIdx.x == 0) { flag[0] = (m == 0ULL) ? 1 : 0; flag[1] = 0; }
    }
}

// Fused: blocks [0,GEMM_BLOCKS) do the GEMM (MFMA/LDS-bound); the rest do the
// XCD-grouped scatter (latency-bound). Co-resident blocks overlap the pipes.
__global__ __launch_bounds__(256) void k_fused(const float* __restrict__ x,
                                               const float* __restrict__ W,
                                               const float* __restrict__ bias,
                                               unsigned short* __restrict__ hidden,
                                               const int* __restrict__ ei,
                                               const float* __restrict__ wt,
                                               int* __restrict__ flag,
                                               int* __restrict__ fill,
                                               unsigned int* __restrict__ slots,
                                               int2* __restrict__ ovf) {
    __shared__ __align__(16) unsigned short Wlds[128 * 136];
    const int t = threadIdx.x;

    if (blockIdx.x < GEMM_BLOCKS) {
        // ---------------- GEMM path ----------------
        for (int j = 0; j < 16; ++j) {
            int idx4 = j * 256 + t;
            float4v wv = *(const float4v*)(W + (size_t)idx4 * 4);
            int r = (idx4 * 4) >> 7;
            int c = (idx4 * 4) & 127;
            unsigned short* p = &Wlds[r * 136 + c];
            p[0] = f2b(wv[0]); p[1] = f2b(wv[1]); p[2] = f2b(wv[2]); p[3] = f2b(wv[3]);
        }
        __syncthreads();

        const int wave = t >> 6;
        const int lane = t & 63;
        int tile = blockIdx.x * 4 + wave;
        if (tile >= N_TILES) tile = N_TILES - 1;    // clamp: redundant work, no divergent exit
        const int rowBase = tile * 16;
        const int m    = lane & 15;
        const int quad = lane >> 4;

        float4v acc[8];
        for (int i = 0; i < 8; ++i) acc[i] = (float4v){0.f, 0.f, 0.f, 0.f};

        for (int kk = 0; kk < 4; ++kk) {
            const int k0 = kk * 32 + quad * 8;
            const float* ap = x + (size_t)(rowBase + m) * FEAT + k0;
            float4v a0 = *(const float4v*)(ap);
            float4v a1 = *(const float4v*)(ap + 4);
            short8 af;
            for (int j = 0; j < 4; ++j) { af[j] = (short)f2b(a0[j]); af[4 + j] = (short)f2b(a1[j]); }
            for (int nt = 0; nt < 8; ++nt) {
                short8 bf = *(const short8*)&Wlds[(nt * 16 + m) * 136 + k0];
                acc[nt] = __builtin_amdgcn_mfma_f32_16x16x32_bf16(af, bf, acc[nt], 0, 0, 0);
            }
        }

        const int r0 = rowBase + quad * 4;          // C/D: col=lane&15, row=quad*4+r
        for (int nt = 0; nt < 8; ++nt) {
            const int col = nt * 16 + m;
            const float bc = bias[col];
            for (int r = 0; r < 4; ++r) {
                hidden[(size_t)(r0 + r) * FEAT + col] = f2b(acc[nt][r] + bc);
            }
        }
    } else {
        // ---------------- scatter path (XCD-grouped) ----------------
        const int bid = blockIdx.x - GEMM_BLOCKS;
        const int grp = bid & 7;
        const int lo  = grp * NODES_PER_GRP;
        const int hi  = lo + NODES_PER_GRP;
        const int sh  = flag[0];
        const int e0  = (bid >> 3) * CHUNK + t;

        int dsts[8];
        #pragma unroll
        for (int i = 0; i < 8; ++i) {
            int e = e0 + i * 256;
            dsts[i] = (e < N_EDGES) ? ei[(size_t)e << sh] : -1;
        }
        #pragma unroll
        for (int i = 0; i < 8; ++i) {
            int e = e0 + i * 256;
            if (e >= N_EDGES) continue;
            int dst = dsts[i];
            if ((unsigned)dst >= N_NODES) dst = 0;
            if (dst < lo || dst >= hi) continue;
            int src = ei[(size_t)(N_EDGES + e) << sh];
            if ((unsigned)src >= N_NODES) src = 0;
            unsigned int rec = ((unsigned int)f2b(wt[e]) << 16) | (unsigned int)src;
            int pos = atomicAdd(&fill[dst], 1);
            if (pos < MAXD) {
                slots[(size_t)dst * MAXD + pos] = rec;
            } else {
                int op = atomicAdd(&flag[1], 1);
                if (op < OVF_CAP) { int2 r; r.x = dst; r.y = (int)rec; ovf[op] = r; }
            }
        }
    }
}

// out[node][:] = sum_slots w_e * hidden[src_e][:]
// wave per node; lane-group g (16 lanes) handles edge e+g; each lane loads 16B
// (8 bf16 feats) -> 1 gather instruction covers 4 edges. fp32 accumulate.
__global__ __launch_bounds__(256) void k_agg(const int* __restrict__ fill,
                                             const unsigned int* __restrict__ slots,
                                             const unsigned int* __restrict__ hid,
                                             const int* __restrict__ flag,
                                             const int2* __restrict__ ovf,
                                             float* __restrict__ out) {
    const int wave = threadIdx.x >> 6;
    const int lane = threadIdx.x & 63;
    const int node = blockIdx.x * 4 + wave;         // grid exact: 12500*4 = 50000
    const int grp  = lane >> 4;
    const int sub  = lane & 15;

    const int degf = fill[node];
    const int deg  = (degf > MAXD) ? MAXD : degf;
    const unsigned int* sl = slots + (size_t)node * MAXD;

    float acc[8];
    #pragma unroll
    for (int j = 0; j < 8; ++j) acc[j] = 0.f;

    for (int e = 0; e < deg; e += 4) {
        uint4 recs = *(const uint4*)(sl + e);                   // 16B broadcast
        unsigned rec = (grp < 2) ? (grp == 0 ? recs.x : recs.y)
                                 : (grp == 2 ? recs.z : recs.w);
        const bool v = (e + grp) < deg;
        const float w = v ? __uint_as_float(rec & 0xffff0000u) : 0.f;
        const unsigned src = v ? (rec & 0xffffu) : 0u;
        uint4 h = *((const uint4*)(hid + (size_t)src * 64) + sub);  // 16B/lane gather
        acc[0] = fmaf(w, __uint_as_float((h.x & 0xffffu) << 16), acc[0]);
        acc[1] = fmaf(w, __uint_as_float(h.x & 0xffff0000u),     acc[1]);
        acc[2] = fmaf(w, __uint_as_float((h.y & 0xffffu) << 16), acc[2]);
        acc[3] = fmaf(w, __uint_as_float(h.y & 0xffff0000u),     acc[3]);
        acc[4] = fmaf(w, __uint_as_float((h.z & 0xffffu) << 16), acc[4]);
        acc[5] = fmaf(w, __uint_as_float(h.z & 0xffff0000u),     acc[5]);
        acc[6] = fmaf(w, __uint_as_float((h.w & 0xffffu) << 16), acc[6]);
        acc[7] = fmaf(w, __uint_as_float(h.w & 0xffff0000u),     acc[7]);
    }

    // rare overflow edges folded in (entry i handled by lane-group i&3)
    if (degf > MAXD) {
        int n = flag[1]; if (n > OVF_CAP) n = OVF_CAP;
        for (int i = 0; i < n; ++i) {
            int2 r = ovf[i];
            if (r.x != node || (i & 3) != grp) continue;
            unsigned rec = (unsigned)r.y;
            float w = __uint_as_float(rec & 0xffff0000u);
            unsigned src = rec & 0xffffu;
            uint4 h = *((const uint4*)(hid + (size_t)src * 64) + sub);
            acc[0] = fmaf(w, __uint_as_float((h.x & 0xffffu) << 16), acc[0]);
            acc[1] = fmaf(w, __uint_as_float(h.x & 0xffff0000u),     acc[1]);
            acc[2] = fmaf(w, __uint_as_float((h.y & 0xffffu) << 16), acc[2]);
            acc[3] = fmaf(w, __uint_as_float(h.y & 0xffff0000u),     acc[3]);
            acc[4] = fmaf(w, __uint_as_float((h.z & 0xffffu) << 16), acc[4]);
            acc[5] = fmaf(w, __uint_as_float(h.z & 0xffff0000u),     acc[5]);
            acc[6] = fmaf(w, __uint_as_float((h.w & 0xffffu) << 16), acc[6]);
            acc[7] = fmaf(w, __uint_as_float(h.w & 0xffff0000u),     acc[7]);
        }
    }

    // combine the 4 lane-groups: butterfly over lane bits 4,5
    #pragma unroll
    for (int j = 0; j < 8; ++j) {
        float a = acc[j];
        a += __shfl_xor(a, 16, 64);
        a += __shfl_xor(a, 32, 64);
        acc[j] = a;
    }

    if (lane < 16) {
        float* o = out + (size_t)node * FEAT + sub * 8;
        *(float4*)(o)     = make_float4(acc[0], acc[1], acc[2], acc[3]);
        *(float4*)(o + 4) = make_float4(acc[4], acc[5], acc[6], acc[7]);
    }
}

extern "C" void kernel_launch(void* const* d_in, const int* in_sizes, int n_in,
                              void* d_out, int out_size, void* d_ws, size_t ws_size,
                              hipStream_t stream) {
    const float* x  = (const float*)d_in[0];
    const int*   ei = (const int*)d_in[1];
    const float* ew = (const float*)d_in[2];
    const float* W  = (const float*)d_in[3];
    const float* b  = (const float*)d_in[4];
    float* out = (float*)d_out;

    int*  flag = (int*)d_ws;
    int*  fill = flag + 16;
    int2* ovf  = (int2*)(fill + 50048);
    unsigned int* slots = (unsigned int*)(ovf + OVF_CAP);
    unsigned short* hidden = (unsigned short*)(slots + (size_t)N_NODES * MAXD);

    k_init <<<(N_NODES + 255) / 256, 256, 0, stream>>>(ei, flag, fill);
    k_fused<<<GEMM_BLOCKS + NCHUNK * 8, 256, 0, stream>>>(x, W, b, hidden, ei, ew,
                                                          flag, fill, slots, ovf);
    k_agg  <<<N_NODES / 4, 256, 0, stream>>>(fill, slots, (const unsigned int*)hidden,
                                             flag, ovf, out);
}